// Round 7
// baseline (165.095 us; speedup 1.0000x reference)
//
#include <hip/hip_runtime.h>
#include <hip/hip_bf16.h>
#include <stdint.h>

// Problem constants: N=16384, M=1024, D=1024, fp32 in/out
#define NN 16384
#define MM 1024
#define DD 1024

typedef __attribute__((ext_vector_type(4)))  int   int4v;
typedef __attribute__((ext_vector_type(8)))  int   int8v;   // 32 fp8 (MX MFMA A/B frag)
typedef __attribute__((ext_vector_type(4)))  float f4;
typedef __attribute__((ext_vector_type(16))) float f16v;    // 32x32 MFMA C/D frag

// pack 4 fp32 -> 4 OCP e4m3 bytes in a dword (HW RNE)
__device__ __forceinline__ uint32_t pk4fp8(float a, float b, float c, float d) {
    uint32_t lo = __builtin_amdgcn_cvt_pk_fp8_f32(a, b, 0, false);
    return __builtin_amdgcn_cvt_pk_fp8_f32(c, d, lo, true);
}

// ---- fused row squared-norms + fp32->fp8 convert, x and centers in one grid ----
__global__ __launch_bounds__(256)
void rowsq_cvt8_all(const float* __restrict__ x, const float* __restrict__ cen,
                    float* __restrict__ xsq, float* __restrict__ csq,
                    uint32_t* __restrict__ x8, uint32_t* __restrict__ c8) {
    int row  = (blockIdx.x * 256 + threadIdx.x) >> 6;
    int lane = threadIdx.x & 63;
    const float* src; float* sq; uint32_t* ob;
    if (row < NN) { src = x + (size_t)row * DD;          sq = xsq + row;        ob = x8 + (size_t)row * (DD / 4); }
    else          { int r = row - NN;
                    src = cen + (size_t)r * DD;          sq = csq + r;          ob = c8 + (size_t)r * (DD / 4); }
    const f4* p = (const f4*)src;
    float s = 0.f;
    for (int i = lane; i < DD / 4; i += 64) {
        f4 v = p[i];
        s = fmaf(v.x, v.x, s); s = fmaf(v.y, v.y, s);
        s = fmaf(v.z, v.z, s); s = fmaf(v.w, v.w, s);
        ob[i] = pk4fp8(v.x, v.y, v.z, v.w);
    }
#pragma unroll
    for (int off = 32; off > 0; off >>= 1) s += __shfl_down(s, off);
    if (lane == 0) *sq = s;
}

// ---- fp32 [k][c] -> fp8 [c][k] transpose+convert (norm) ----
__global__ __launch_bounds__(256)
void trcvt8(const float* __restrict__ in, uint8_t* __restrict__ out) {
    __shared__ float t[32][33];
    int tx = threadIdx.x & 31, ty = threadIdx.x >> 5;  // 32 x 8
    int bx = blockIdx.x, by = blockIdx.y;
#pragma unroll
    for (int i = 0; i < 32; i += 8)
        t[ty + i][tx] = in[(size_t)(by * 32 + ty + i) * MM + bx * 32 + tx];
    __syncthreads();
    int c  = threadIdx.x >> 3;
    int rg = (threadIdx.x & 7) * 4;
    uint32_t u = pk4fp8(t[rg + 0][c], t[rg + 1][c], t[rg + 2][c], t[rg + 3][c]);
    *(uint32_t*)&out[(size_t)(bx * 32 + c) * MM + by * 32 + rg] = u;
}

// ---- MX-fp8 MFMA GEMM, persistent: 512 blocks x 2 tiles (shared B col-panel) ----
// Round-7 change: K=1024 gives only 8 K-iters/tile -- pipeline fill/drain and
// cold-load latency were ~35% of block life. Each block now runs a flat
// 16-iter loop over two row-panels of the same column panel: tile 2's first
// prefetch issues during tile 1's last MFMAs + epilogue (no drain), B panel
// is L2-hot on the second pass, and the dispatch tail halves.
// 32x32x64 MX MFMA (scales=1.0), reg-prefetch -> ds_write pipeline (32 KB LDS,
// ~3 blocks/CU), XOR-swizzled 16B chunks (round-4), XCD swizzle (round-3).
constexpr int BM = 128, BN = 128, BK = 128;

template<bool EXP_EPI>
__global__ __launch_bounds__(256)
void mfma_gemm_fp8(const uint8_t* __restrict__ A, const uint8_t* __restrict__ Bt,
                   void* __restrict__ Cv, const float* __restrict__ xsq,
                   const float* __restrict__ csq, const float* __restrict__ gamma_p)
{
    constexpr int K = 1024, NC = 1024, NIT = K / BK;   // 8 iters/tile
    __shared__ __align__(16) uint8_t sA[BM * BK];  // 16 KB, sA[r][c16]=G[r][c16^(r&7)]
    __shared__ __align__(16) uint8_t sB[BN * BK];  // 16 KB

    const int tid  = threadIdx.x;
    const int lane = tid & 63;
    const int wave = tid >> 6;
    const int l31  = lane & 31;
    const int kh   = lane >> 5;
    const int wm   = (wave >> 1) * 64;
    const int wn   = (wave & 1) * 64;

    // XCD swizzle: pid&7 = xcd (HW round-robin). Each XCD owns its 16
    // row-panels; a block's two tiles share bcol (B panel L2-hot).
    const int pid  = blockIdx.x;           // 0..511
    const int xcd  = pid & 7;
    const int s0   = pid >> 3;             // 0..63 -> tiles s0, s0+64
    const int bx   = s0 & 7;
    const int bcol = bx * BN;
    const int brow0 = ((xcd << 4) | (s0 >> 3)) * BM;
    const int brow1 = ((xcd << 4) | ((s0 + 64) >> 3)) * BM;

    // staging coords: thread covers rows {wave*32 + i*8 + r8}, 16B chunk c8
    const int r8 = lane >> 3;
    const int c8 = lane & 7;
    const int wc = c8 ^ r8;                // XOR-swizzled LDS chunk

    const float gam = EXP_EPI ? gamma_p[0] : 0.f;
    float cs[2];
    if constexpr (EXP_EPI) {
        cs[0] = csq[bcol + wn + l31];
        cs[1] = csq[bcol + wn + 32 + l31];
    }

    const size_t aoff[2] = {(size_t)(brow0 + wave * 32 + r8) * K,
                            (size_t)(brow1 + wave * 32 + r8) * K};
    const uint8_t* gbb = Bt + (size_t)(bcol + wave * 32 + r8) * K + c8 * 16;
    uint8_t* wa = &sA[(wave * 32 + r8) * BK + wc * 16];
    uint8_t* wb = &sB[(wave * 32 + r8) * BK + wc * 16];

    f16v acc[2][2];
#pragma unroll
    for (int mi = 0; mi < 2; ++mi)
#pragma unroll
        for (int ni = 0; ni < 2; ++ni)
#pragma unroll
            for (int r = 0; r < 16; ++r) acc[mi][ni][r] = 0.f;

    // prologue: prefetch tile 0, k=0
    int4v pf[8];
#pragma unroll
    for (int i = 0; i < 4; ++i) {
        pf[i]     = *(const int4v*)(A + aoff[0] + c8 * 16 + (size_t)i * 8 * K);
        pf[4 + i] = *(const int4v*)(gbb + (size_t)i * 8 * K);
    }

#pragma unroll
    for (int it = 0; it < 2 * NIT; ++it) {
        __syncthreads();               // all waves done reading previous tile
#pragma unroll
        for (int i = 0; i < 4; ++i) {  // commit prefetched k-tile (loads landed)
            *(int4v*)(wa + i * 8 * BK) = pf[i];
            *(int4v*)(wb + i * 8 * BK) = pf[4 + i];
        }
        __syncthreads();               // tile visible
        if (it + 1 < 2 * NIT) {        // prefetch next k-tile (crosses tiles!)
            const int nt = (it + 1) >> 3, ko = ((it + 1) & (NIT - 1)) * BK;
#pragma unroll
            for (int i = 0; i < 4; ++i) {
                pf[i]     = *(const int4v*)(A + aoff[nt] + ko + c8 * 16 + (size_t)i * 8 * K);
                pf[4 + i] = *(const int4v*)(gbb + ko + (size_t)i * 8 * K);
            }
        }
#pragma unroll
        for (int s = 0; s < 2; ++s) {  // two 64-deep k-steps
            const int cb = s * 4 + kh * 2;
            int8v a[2], b[2];
#pragma unroll
            for (int mi = 0; mi < 2; ++mi) {
                int row = wm + mi * 32 + l31;
                const uint8_t* base = &sA[row * BK];
                int4v lo = *(const int4v*)(base + ((cb ^ (row & 7)) * 16));
                int4v hi = *(const int4v*)(base + (((cb + 1) ^ (row & 7)) * 16));
                a[mi] = __builtin_shufflevector(lo, hi, 0, 1, 2, 3, 4, 5, 6, 7);
            }
#pragma unroll
            for (int ni = 0; ni < 2; ++ni) {
                int col = wn + ni * 32 + l31;
                const uint8_t* base = &sB[col * BK];
                int4v lo = *(const int4v*)(base + ((cb ^ (col & 7)) * 16));
                int4v hi = *(const int4v*)(base + (((cb + 1) ^ (col & 7)) * 16));
                b[ni] = __builtin_shufflevector(lo, hi, 0, 1, 2, 3, 4, 5, 6, 7);
            }
#pragma unroll
            for (int mi = 0; mi < 2; ++mi)
#pragma unroll
                for (int ni = 0; ni < 2; ++ni)
                    acc[mi][ni] = __builtin_amdgcn_mfma_scale_f32_32x32x64_f8f6f4(
                        a[mi], b[ni], acc[mi][ni],
                        0, 0, 0, 0x7F7F7F7F, 0, 0x7F7F7F7F);  // fp8, scales=1.0
        }

        if ((it & (NIT - 1)) == NIT - 1) {
            // epilogue for finished tile; next tile's first prefetch is in flight
            const int brow = (it >> 3) ? brow1 : brow0;
            // C/D layout (32x32, m74/m101): col=lane&31, row=(reg&3)+8*(reg>>2)+4*kh
            if constexpr (EXP_EPI) {
                uint8_t* C = (uint8_t*)Cv;
#pragma unroll
                for (int mi = 0; mi < 2; ++mi)
#pragma unroll
                    for (int r = 0; r < 16; ++r) {
                        int rl  = (r & 3) + 8 * (r >> 2) + 4 * kh;
                        int row = brow + wm + mi * 32 + rl;
                        float xs = xsq[row];
#pragma unroll
                        for (int ni = 0; ni < 2; ++ni) {
                            int col = bcol + wn + ni * 32 + l31;
                            float sq = xs + cs[ni] - 2.0f * acc[mi][ni][r];
                            float d = __expf(-gam * sq);  // underflows (sq ~>1500)
                            C[(size_t)row * NC + col] =
                                (uint8_t)(__builtin_amdgcn_cvt_pk_fp8_f32(d, d, 0, false) & 0xFF);
                        }
                    }
            } else {
                float* C = (float*)Cv;
#pragma unroll
                for (int mi = 0; mi < 2; ++mi)
#pragma unroll
                    for (int r = 0; r < 16; ++r) {
                        int rl  = (r & 3) + 8 * (r >> 2) + 4 * kh;
                        int row = brow + wm + mi * 32 + rl;
#pragma unroll
                        for (int ni = 0; ni < 2; ++ni)
                            C[(size_t)row * NC + bcol + wn + ni * 32 + l31] = acc[mi][ni][r];
                    }
            }
#pragma unroll
            for (int mi = 0; mi < 2; ++mi)   // reset accumulator for tile 2
#pragma unroll
                for (int ni = 0; ni < 2; ++ni)
#pragma unroll
                    for (int r = 0; r < 16; ++r) acc[mi][ni][r] = 0.f;
        }
    }
}

extern "C" void kernel_launch(void* const* d_in, const int* in_sizes, int n_in,
                              void* d_out, int out_size, void* d_ws, size_t ws_size,
                              hipStream_t stream) {
    const float* inputs  = (const float*)d_in[0];   // [N, D]
    const float* centers = (const float*)d_in[1];   // [M, D]
    const float* gamma   = (const float*)d_in[2];   // [1]
    const float* norm    = (const float*)d_in[3];   // [M, M]
    float* out = (float*)d_out;                     // [N, M]

    // ws layout: xsq 64K | csq 4K | c8 1M | n8 1M | dens8 16M  (~18.1 MiB)
    char* w = (char*)d_ws;
    float*   xsq   = (float*)w;
    float*   csq   = (float*)(w + 65536);
    uint8_t* c8    = (uint8_t*)(w + 69632);
    uint8_t* n8    = (uint8_t*)(w + 69632 + (1u << 20));
    uint8_t* dens8 = (uint8_t*)(w + 69632 + (2u << 20));
    // x in fp8 parked in d_out (16 of its 64 MiB): dead before stage 2 writes.
    uint32_t* x8   = (uint32_t*)d_out;

    rowsq_cvt8_all<<<(NN + MM) / 4, 256, 0, stream>>>(
        inputs, centers, xsq, csq, x8, (uint32_t*)c8);
    trcvt8<<<dim3(32, 32), 256, 0, stream>>>(norm, n8);

    // stage 1: dens = exp(-g * (xsq + csq - 2 * x @ centers^T)), fp8 out
    mfma_gemm_fp8<true><<<512, 256, 0, stream>>>(
        (const uint8_t*)x8, c8, dens8, xsq, csq, gamma);
    // stage 2: out = dens @ norm (via norm^T), fp32 out
    mfma_gemm_fp8<false><<<512, 256, 0, stream>>>(
        dens8, n8, out, nullptr, nullptr, nullptr);
}